// Round 9
// baseline (215.911 us; speedup 1.0000x reference)
//
#include <hip/hip_runtime.h>
#include <hip/hip_bf16.h>

// Problem constants
#define B_   8
#define D1_  1024
#define DJ_  512
#define S_   2048
#define OUT_ 2048
#define IN_  2048          // D1 + 2*DJ
#define M_TOT (B_ * S_)    // 16384

typedef __attribute__((ext_vector_type(8))) short          bf16x8;
typedef __attribute__((ext_vector_type(8))) unsigned short ushort8;
typedef __attribute__((ext_vector_type(4))) float          f32x4;

typedef __attribute__((address_space(3))) unsigned int as3_uint;
typedef __attribute__((address_space(1))) unsigned int as1_uint;

__device__ __forceinline__ unsigned short f2bf(float f) {
    union { float f; unsigned u; } v; v.f = f;
    unsigned r = v.u + 0x7FFF + ((v.u >> 16) & 1);   // round-to-nearest-even
    return (unsigned short)(r >> 16);
}

__device__ __forceinline__ void gload_lds16(const void* g, const void* l) {
    __builtin_amdgcn_global_load_lds(
        (const as1_uint*)(unsigned long long)g,
        (as3_uint*)(unsigned int)(unsigned long long)l,
        16, 0, 0);
}

// ---------------------------------------------------------------------------
// Kernel 1 (merged prep, == round 7): blocks [0,8192) = concat+transpose+cvt;
// blocks [8192,10240) = W f32->bf16.
__global__ __launch_bounds__(256) void prep_kernel(
        const float* __restrict__ in1, const float* __restrict__ in2a,
        const float* __restrict__ in2b, const float* __restrict__ W,
        unsigned short* __restrict__ Xt, unsigned short* __restrict__ Wb) {
    int bid = blockIdx.x;
    if (bid >= 8192) {
        size_t i = (size_t)(bid - 8192) * 256 + threadIdx.x;
        const float4* p = reinterpret_cast<const float4*>(W) + i * 2;
        float4 a = p[0], c = p[1];
        ushort8 h;
        h[0] = f2bf(a.x); h[1] = f2bf(a.y); h[2] = f2bf(a.z); h[3] = f2bf(a.w);
        h[4] = f2bf(c.x); h[5] = f2bf(c.y); h[6] = f2bf(c.z); h[7] = f2bf(c.w);
        *(reinterpret_cast<ushort8*>(Wb) + i) = h;
        return;
    }
    __shared__ float tile[64][65];
    int st = bid & 31;
    int ft = (bid >> 5) & 31;
    int b  = bid >> 10;
    int f0 = ft << 6, s0 = st << 6;

    const float* src; int frel;
    if (f0 < D1_)             { src = in1  + (size_t)b * D1_ * S_; frel = f0; }
    else if (f0 < D1_ + DJ_)  { src = in2a + (size_t)b * DJ_ * S_; frel = f0 - D1_; }
    else                      { src = in2b + (size_t)b * DJ_ * S_; frel = f0 - (D1_ + DJ_); }

    int t = threadIdx.x;
    int tr = t >> 4, tc = t & 15;
    #pragma unroll
    for (int i = 0; i < 4; ++i) {
        int fi = tr + i * 16;
        const float4 v = *reinterpret_cast<const float4*>(
            &src[(size_t)(frel + fi) * S_ + s0 + tc * 4]);
        tile[fi][tc * 4 + 0] = v.x; tile[fi][tc * 4 + 1] = v.y;
        tile[fi][tc * 4 + 2] = v.z; tile[fi][tc * 4 + 3] = v.w;
    }
    __syncthreads();
    int si0 = t >> 3, fx = t & 7;
    #pragma unroll
    for (int i = 0; i < 2; ++i) {
        int si = si0 + i * 32;
        ushort8 h;
        #pragma unroll
        for (int j = 0; j < 8; ++j) h[j] = f2bf(tile[fx * 8 + j][si]);
        *reinterpret_cast<ushort8*>(
            &Xt[(size_t)(b * S_ + s0 + si) * IN_ + f0 + fx * 8]) = h;
    }
}

// ---------------------------------------------------------------------------
// Kernel 2: 256x256 bf16 GEMM, B DIRECT-TO-REGISTER (round 9).
// C[M,N] = A[M,K] * B[N,K]^T + bias.  512 thr = 8 waves (2M x 4N).
// LDS: As_ ONLY, [2 buf][2 region][128][64] bf16 = 64 KiB (Bs_ deleted).
// A path unchanged (gload_lds + T2 swizzle).  B fragments are loaded straight
// from global Wb into registers (dwordx4, L2-resident: each XCD owns ONE
// 1 MB n-panel via ntile = bid&7).
//
// Per SP (one K-tile t from buf bb; 1 barrier):
//   issue order: A(t+1) 4 gload_lds | Bq0(t+1) 4 dwordx4 | [mid] Bq1(t+1) 4.
//   fence-1 vmcnt(8) before burst 1: drains Bq0(t)/Bq1(t) (issued >=1 SP ago,
//     ~2800 cyc slack vs L2 ~200) -> no stall.  Leaves [A(t+1), Bq0(t+1)].
//   end fence vmcnt(8): drains A(t+1) (issued SP-top, ~2500 cyc slack vs HBM
//     ~900) -> no stall.  Leaves the 8 B(t+1) loads in flight across the
//     barrier (counted, never 0 in main loop).
//   B-regs: 4 named sets, parity ping-pong (static indexing, no spill-prone
//     runtime idx).  WAR: overwritten set's last reader retired before the
//     previous SP's end barrier.  LDS WAR/RAW as r7 (1-barrier discipline).

__global__ __launch_bounds__(512, 2) void gemm256_kernel(
        const unsigned short* __restrict__ A,    // Xt [M_TOT][IN_] bf16
        const unsigned short* __restrict__ Bm,   // Wb [OUT_][IN_] bf16
        const float* __restrict__ bias,
        float* __restrict__ C) {
    __shared__ unsigned short As_[32768];   // [2][2][128][64] = 64 KiB

    int bid = blockIdx.x;
    // XCD-resident B: XCD = bid&7 owns ntile = bid&7 (W panel 1MB -> L2).
    int ntile = bid & 7;
    int mtile = bid >> 3;
    int m0 = mtile * 256, n0 = ntile * 256;

    int t = threadIdx.x;
    int lane = t & 63, wave = t >> 6;
    int wm = wave >> 2;            // 0..1
    int wn = wave & 3;             // 0..3
    int fr = lane & 15;
    int fkslot = lane >> 4;        // 0..3

    // A staging constants (gload_lds path, pre-swizzled source)
    int sr  = t >> 3;              // 0..63
    int sc  = t & 7;               // 16B slot
    int swc = sc ^ (sr & 7);       // pre-swizzled global k-slot (involution)

    // ds_read swizzled slot offsets (elements) for kk=0,1
    int sl0 = ((fkslot)     ^ (fr & 7)) * 8;
    int sl1 = ((4 + fkslot) ^ (fr & 7)) * 8;
    int arow = wm * 64 + fr;       // A region-local row base

#define STAGE_A(bb, h, kt) do { \
    const unsigned short* _g0 = A + (size_t)(m0 + (h)*64 + sr) * IN_ + (kt) + swc*8; \
    const unsigned short* _g1 = A + (size_t)(m0 + 128 + (h)*64 + sr) * IN_ + (kt) + swc*8; \
    unsigned short* _l = As_ + ((bb)*2 + (h))*8192 + sr*64 + sc*8; \
    gload_lds16(_g0, _l); \
    gload_lds16(_g1, _l + 4096); \
} while (0)

#define READ_A(bb, qm) do { \
    const unsigned short* _Ab = As_ + ((bb)*2 + (qm))*8192; \
    _Pragma("unroll") \
    for (int i = 0; i < 4; ++i) { \
        int rr = (arow + i*16) * 64; \
        a_[i][0] = *reinterpret_cast<const bf16x8*>(_Ab + rr + sl0); \
        a_[i][1] = *reinterpret_cast<const bf16x8*>(_Ab + rr + sl1); \
    } \
} while (0)

// B quadrant qn rows: n0 + wn*64 + qn*32 + j*16 + fr;  k: ktn + kk*32 + fkslot*8
#define LOADB_Q(DST, qn, ktn) do { \
    _Pragma("unroll") \
    for (int _j = 0; _j < 2; ++_j) { \
        _Pragma("unroll") \
        for (int _kk = 0; _kk < 2; ++_kk) { \
            DST[_j][_kk] = *reinterpret_cast<const bf16x8*>( \
                Bm + (size_t)(n0 + wn*64 + (qn)*32 + _j*16 + fr) * IN_ \
                   + (ktn) + _kk*32 + fkslot*8); \
        } \
    } \
} while (0)

#define MFMA4(qm, qn, BS) \
    _Pragma("unroll") \
    for (int i = 0; i < 4; ++i) { \
        _Pragma("unroll") \
        for (int j = 0; j < 2; ++j) { \
            acc[(qm)*4+i][(qn)*2+j] = __builtin_amdgcn_mfma_f32_16x16x32_bf16( \
                a_[i][0], BS[j][0], acc[(qm)*4+i][(qn)*2+j], 0, 0, 0); \
            acc[(qm)*4+i][(qn)*2+j] = __builtin_amdgcn_mfma_f32_16x16x32_bf16( \
                a_[i][1], BS[j][1], acc[(qm)*4+i][(qn)*2+j], 0, 0, 0); \
        } \
    }

#define LGKM0 do { \
    asm volatile("s_waitcnt lgkmcnt(0)" ::: "memory"); \
    __builtin_amdgcn_sched_barrier(0); \
} while (0)

#define VMN(n) do { \
    asm volatile("s_waitcnt vmcnt(" #n ")" ::: "memory"); \
    __builtin_amdgcn_sched_barrier(0); \
} while (0)

// SP computing K-tile t from buf bb with sets BC0/BC1; stages t+1 (= ktn)
// into buf bb^1 and loads B(t+1) into BN0/BN1.
#define SP(bb, BC0, BC1, BN0, BN1, ktn) do { \
    STAGE_A((bb)^1, 0, ktn); \
    STAGE_A((bb)^1, 1, ktn); \
    LOADB_Q(BN0, 0, ktn); \
    READ_A(bb, 0); \
    VMN(8); \
    LGKM0; \
    __builtin_amdgcn_s_setprio(1); \
    MFMA4(0, 0, BC0) \
    MFMA4(0, 1, BC1) \
    __builtin_amdgcn_s_setprio(0); \
    READ_A(bb, 1); \
    LOADB_Q(BN1, 1, ktn); \
    LGKM0; \
    __builtin_amdgcn_s_setprio(1); \
    MFMA4(1, 1, BC1) \
    MFMA4(1, 0, BC0) \
    __builtin_amdgcn_s_setprio(0); \
    VMN(8); \
    __builtin_amdgcn_s_barrier(); \
} while (0)

    f32x4 acc[8][4] = {};
    bf16x8 a_[4][2];
    bf16x8 bq0A[2][2], bq1A[2][2], bq0B[2][2], bq1B[2][2];

    // Prologue: stage K-tile 0 -> buf0; load B(0) into the A-parity sets.
    STAGE_A(0, 0, 0);
    STAGE_A(0, 1, 0);
    LOADB_Q(bq0A, 0, 0);
    LOADB_Q(bq1A, 1, 0);
    VMN(0);
    __builtin_amdgcn_s_barrier();

    // 32 K-tiles: even t uses A-parity sets (buf0), odd t uses B-parity (buf1).
    // Last stage wraps to kt=0 (dead loads, valid addresses, never consumed).
    for (int it = 0; it < IN_ / 128; ++it) {
        int k1 = it * 128 + 64;
        int k2 = (it * 128 + 128) & (IN_ - 1);
        SP(0, bq0A, bq1A, bq0B, bq1B, k1);
        SP(1, bq0B, bq1B, bq0A, bq1A, k2);
    }

    // Epilogue: bias + store. C/D layout: col = lane&15, row = (lane>>4)*4 + reg.
    float bv[4];
    #pragma unroll
    for (int n_ = 0; n_ < 4; ++n_) bv[n_] = bias[n0 + wn * 64 + n_ * 16 + fr];
    int crow0 = m0 + wm * 128 + (lane >> 4) * 4;
    int ccol0 = n0 + wn * 64 + fr;
    #pragma unroll
    for (int mi = 0; mi < 8; ++mi) {
        #pragma unroll
        for (int r_ = 0; r_ < 4; ++r_) {
            float* cp = C + (size_t)(crow0 + mi * 16 + r_) * OUT_ + ccol0;
            #pragma unroll
            for (int n_ = 0; n_ < 4; ++n_) cp[n_ * 16] = acc[mi][n_][r_] + bv[n_];
        }
    }
#undef STAGE_A
#undef READ_A
#undef LOADB_Q
#undef MFMA4
#undef LGKM0
#undef VMN
#undef SP
}

// ---------------------------------------------------------------------------
// Fallback (only if workspace too small): naive fp32, correct but slow.
__global__ __launch_bounds__(256) void naive_kernel(
        const float* __restrict__ in1, const float* __restrict__ in2a,
        const float* __restrict__ in2b, const float* __restrict__ W,
        const float* __restrict__ bias, float* __restrict__ out) {
    size_t id = (size_t)blockIdx.x * 256 + threadIdx.x;
    int s = (int)(id & (S_ - 1));
    size_t bo = id >> 11;
    int o = (int)(bo & (OUT_ - 1));
    int b = (int)(bo >> 11);
    const float* w = W + (size_t)o * IN_;
    float acc = bias[o];
    const float* x1 = in1 + (size_t)b * D1_ * S_ + s;
    for (int f = 0; f < D1_; ++f) acc += x1[(size_t)f * S_] * w[f];
    const float* x2 = in2a + (size_t)b * DJ_ * S_ + s;
    for (int f = 0; f < DJ_; ++f) acc += x2[(size_t)f * S_] * w[D1_ + f];
    const float* x3 = in2b + (size_t)b * DJ_ * S_ + s;
    for (int f = 0; f < DJ_; ++f) acc += x3[(size_t)f * S_] * w[D1_ + DJ_ + f];
    out[((size_t)b * S_ + s) * OUT_ + o] = acc;
}

// ---------------------------------------------------------------------------
extern "C" void kernel_launch(void* const* d_in, const int* in_sizes, int n_in,
                              void* d_out, int out_size, void* d_ws, size_t ws_size,
                              hipStream_t stream) {
    const float* in1  = (const float*)d_in[0];
    const float* in2a = (const float*)d_in[1];
    const float* in2b = (const float*)d_in[2];
    const float* W    = (const float*)d_in[3];
    const float* bias = (const float*)d_in[4];
    float* out = (float*)d_out;

    const size_t xt_bytes = (size_t)M_TOT * IN_ * 2;   // 67,108,864
    const size_t wb_bytes = (size_t)OUT_ * IN_ * 2;    //  8,388,608

    if (ws_size < xt_bytes + wb_bytes) {
        naive_kernel<<<(B_ * (size_t)OUT_ * S_) / 256, 256, 0, stream>>>(
            in1, in2a, in2b, W, bias, out);
        return;
    }

    unsigned short* Xt = (unsigned short*)d_ws;
    unsigned short* Wb = (unsigned short*)((char*)d_ws + xt_bytes);

    prep_kernel<<<8192 + (OUT_ * IN_) / (256 * 8), 256, 0, stream>>>(
        in1, in2a, in2b, W, Xt, Wb);
    gemm256_kernel<<<(M_TOT / 256) * (OUT_ / 256), 512, 0, stream>>>(Xt, Wb, bias, out);
}